// Round 17
// baseline (748.549 us; speedup 1.0000x reference)
//
#include <hip/hip_runtime.h>
#include <hip/hip_bf16.h>
#include <cstdint>

#define NTOK   10240      // 5*2048 tokens
#define DIM    1024
#define NEXP   8
#define HDIM   4096
#define NSLOT  20480      // NTOK * top2
#define MAXSLOT 21504     // padded to 128 per expert (168*128)
#define MAXTILES 168

typedef __attribute__((ext_vector_type(8))) __bf16 bf16x8;
typedef __attribute__((ext_vector_type(4))) float  f32x4;

__device__ __forceinline__ unsigned short f2bf(float f){
  uint32_t u = __float_as_uint(f);
  uint32_t r = (u + 0x7fffu + ((u >> 16) & 1u)) >> 16;   // RNE
  return (unsigned short)r;
}
__device__ __forceinline__ float bf2f(unsigned short u){
  return __uint_as_float(((uint32_t)u) << 16);
}

__device__ __forceinline__ void gl_lds16(const void* g, void* l){
  __builtin_amdgcn_global_load_lds(
      (const __attribute__((address_space(1))) void*)g,
      (__attribute__((address_space(3))) void*)l, 16, 0, 0);
}

// bijective XCD swizzle (m204)
__device__ __forceinline__ int swz_wid(){
  int nwg = (int)(gridDim.x * gridDim.y);
  int h   = (int)(blockIdx.y * gridDim.x + blockIdx.x);
  int q = nwg >> 3, r = nwg & 7;
  int xcd = h & 7, idx = h >> 3;
  return (xcd < r ? xcd*(q+1) : r*(q+1) + (xcd-r)*q) + idx;
}

// ---------------- Threefry2x32 (JAX partitionable path) ----------------
__device__ __forceinline__ uint32_t rotl32(uint32_t x, int n){ return (x << n) | (x >> (32 - n)); }

__device__ __forceinline__ uint32_t threefry_xor(uint32_t k0, uint32_t k1, uint32_t x0, uint32_t x1){
  uint32_t ks2 = k0 ^ k1 ^ 0x1BD11BDAu;
  uint32_t ks[3] = {k0, k1, ks2};
  x0 += ks[0]; x1 += ks[1];
  const int rA[4] = {13,15,26,6};
  const int rB[4] = {17,29,16,24};
  #pragma unroll
  for (int i = 0; i < 5; ++i){
    #pragma unroll
    for (int j = 0; j < 4; ++j){
      int rot = (i & 1) ? rB[j] : rA[j];
      x0 += x1; x1 = rotl32(x1, rot); x1 ^= x0;
    }
    x0 += ks[(i+1)%3];
    x1 += ks[(i+2)%3] + (uint32_t)(i+1);
  }
  return x0 ^ x1;
}

// XLA f32 ErfInv (Giles polynomial)
__device__ __forceinline__ float erfinv_f32(float x){
  float w = -log1pf(-x*x);
  float p;
  if (w < 5.0f){
    w -= 2.5f;
    p = 2.81022636e-08f;
    p = fmaf(p, w, 3.43273939e-07f);
    p = fmaf(p, w, -3.5233877e-06f);
    p = fmaf(p, w, -4.39150654e-06f);
    p = fmaf(p, w, 0.00021858087f);
    p = fmaf(p, w, -0.00125372503f);
    p = fmaf(p, w, -0.00417768164f);
    p = fmaf(p, w, 0.246640727f);
    p = fmaf(p, w, 1.50140941f);
  } else {
    w = sqrtf(w) - 3.0f;
    p = -0.000200214257f;
    p = fmaf(p, w, 0.000100950558f);
    p = fmaf(p, w, 0.00134934322f);
    p = fmaf(p, w, -0.00367342844f);
    p = fmaf(p, w, 0.00573950773f);
    p = fmaf(p, w, -0.0076224613f);
    p = fmaf(p, w, 0.00943887047f);
    p = fmaf(p, w, 1.00167406f);
    p = fmaf(p, w, 2.83297682f);
  }
  return p * x;
}

// ---------------- merged weight transposes ----------------
__device__ __forceinline__ void transpose_body(const float* __restrict__ src,
                                               unsigned short* __restrict__ dst,
                                               int R_, int C_, int bx, int by, int z){
  __shared__ float tile[32][33];
  const int tx = threadIdx.x & 31, ty = threadIdx.x >> 5;
  const float* s = src + (size_t)z * R_ * C_;
  unsigned short* d = dst + (size_t)z * R_ * C_;
  int c0 = bx * 32, r0 = by * 32;
  #pragma unroll
  for (int i = ty; i < 32; i += 8)
    tile[i][tx] = s[(size_t)(r0 + i) * C_ + c0 + tx];
  __syncthreads();
  #pragma unroll
  for (int i = ty; i < 32; i += 8)
    d[(size_t)(c0 + i) * R_ + r0 + tx] = f2bf(tile[tx][i]);
}

__global__ __launch_bounds__(256) void transpose_both_kernel(
    const float* __restrict__ W1, const float* __restrict__ W2,
    unsigned short* __restrict__ W1t, unsigned short* __restrict__ W2t)
{
  int i = (int)blockIdx.x;
  if (i < 32768){   // W1 [8][1024][4096] -> W1t [8][4096][1024]
    transpose_body(W1, W1t, DIM, HDIM, i & 127, (i >> 7) & 31, i >> 12);
  } else {          // W2 [8][4096][1024] -> W2t [8][1024][4096]
    i -= 32768;
    transpose_body(W2, W2t, HDIM, DIM, i & 31, (i >> 5) & 127, i >> 12);
  }
}

// ---------------- routing: 4 waves/block, 1 wave per token ----------------
__global__ __launch_bounds__(256) void route_kernel(
    const float* __restrict__ x, const int* __restrict__ moe,
    const float* __restrict__ Wr, const float* __restrict__ br,
    const float* __restrict__ Wn, const float* __restrict__ bn,
    float* __restrict__ topi_out, int* __restrict__ te, float* __restrict__ tgv,
    unsigned short* __restrict__ xb)
{
  const int wv = threadIdx.x >> 6, lane = threadIdx.x & 63;
  const int tok = (int)blockIdx.x * 4 + wv;
  const int b = tok >> 11;
  const int r = moe[b];
  const float4* xr  = (const float4*)(x + (size_t)tok * DIM);
  const float4* wrp = (const float4*)(Wr + (size_t)r * DIM * NEXP);
  const float4* wnp = (const float4*)(Wn + (size_t)r * DIM * NEXP);
  ushort4* xbrow = (ushort4*)(xb + (size_t)tok * DIM);

  float lg[8], nl[8];
  #pragma unroll
  for (int e = 0; e < 8; ++e){ lg[e] = 0.f; nl[e] = 0.f; }

  #pragma unroll
  for (int it = 0; it < 4; ++it){
    int d4 = it*64 + lane;
    float4 xv = xr[d4];
    ushort4 o;
    o.x = f2bf(xv.x); o.y = f2bf(xv.y); o.z = f2bf(xv.z); o.w = f2bf(xv.w);
    xbrow[d4] = o;
    #pragma unroll
    for (int j = 0; j < 4; ++j){
      float xs = (j==0) ? xv.x : (j==1) ? xv.y : (j==2) ? xv.z : xv.w;
      float4 w0 = wrp[d4*8 + j*2], w1 = wrp[d4*8 + j*2 + 1];
      float4 n0 = wnp[d4*8 + j*2], n1 = wnp[d4*8 + j*2 + 1];
      lg[0] = fmaf(xs, w0.x, lg[0]); lg[1] = fmaf(xs, w0.y, lg[1]);
      lg[2] = fmaf(xs, w0.z, lg[2]); lg[3] = fmaf(xs, w0.w, lg[3]);
      lg[4] = fmaf(xs, w1.x, lg[4]); lg[5] = fmaf(xs, w1.y, lg[5]);
      lg[6] = fmaf(xs, w1.z, lg[6]); lg[7] = fmaf(xs, w1.w, lg[7]);
      nl[0] = fmaf(xs, n0.x, nl[0]); nl[1] = fmaf(xs, n0.y, nl[1]);
      nl[2] = fmaf(xs, n0.z, nl[2]); nl[3] = fmaf(xs, n0.w, nl[3]);
      nl[4] = fmaf(xs, n1.x, nl[4]); nl[5] = fmaf(xs, n1.y, nl[5]);
      nl[6] = fmaf(xs, n1.z, nl[6]); nl[7] = fmaf(xs, n1.w, nl[7]);
    }
  }

  #pragma unroll
  for (int e = 0; e < 8; ++e){
    #pragma unroll
    for (int s = 32; s >= 1; s >>= 1){
      lg[e] += __shfl_xor(lg[e], s, 64);
      nl[e] += __shfl_xor(nl[e], s, 64);
    }
  }

  int el = lane & 7;
  float mylg = lg[0], mynl = nl[0];
  #pragma unroll
  for (int e = 1; e < 8; ++e){
    if (el == e){ mylg = lg[e]; mynl = nl[e]; }
  }
  float logit = mylg + br[r*NEXP + el];
  float nlg   = mynl + bn[r*NEXP + el];
  uint32_t idx  = (uint32_t)(tok*NEXP + el);
  uint32_t bits = threefry_xor(0u, 42u, 0u, idx);
  float u01 = __uint_as_float((bits >> 9) | 0x3f800000u) - 1.0f;
  const float lo = -0.99999994f;
  float uu  = fmaxf(lo, u01 * 2.0f + lo);
  float eps = 1.41421356237f * erfinv_f32(uu);
  float ax = fabsf(nlg);
  float sp = fmaxf(nlg, 0.0f) + log1pf(expf(-ax));
  float noisy = logit + eps * sp;

  float nv[8];
  #pragma unroll
  for (int e = 0; e < 8; ++e) nv[e] = __shfl(noisy, e, 64);

  if (lane == 0){
    int i0 = 0; float v0 = nv[0];
    int i1 = -1; float v1 = -3.4e38f;
    #pragma unroll
    for (int e = 1; e < 8; ++e){
      float v = nv[e];
      if (v > v0){ v1 = v0; i1 = i0; v0 = v; i0 = e; }
      else if (v > v1){ v1 = v; i1 = e; }
    }
    float t = expf(v1 - v0);
    float s = 1.0f + t;
    topi_out[tok*2 + 0] = (float)i0;
    topi_out[tok*2 + 1] = (float)i1;
    te[tok*2 + 0] = i0; te[tok*2 + 1] = i1;
    tgv[tok*2 + 0] = 1.0f / s; tgv[tok*2 + 1] = t / s;
  }
}

// ---------------- count / tables / scatter ----------------
// hdr: [0..8) counts, [8..16) cursor, [16] ntiles
__global__ __launch_bounds__(256) void count_kernel(const int* __restrict__ te,
                                                    unsigned* __restrict__ counts){
  int id = blockIdx.x * 256 + threadIdx.x;
  int e = te[id];
  int lane = threadIdx.x & 63;
  #pragma unroll
  for (int ee = 0; ee < 8; ++ee){
    unsigned long long m = __ballot(e == ee);
    if (m && lane == (__ffsll((unsigned long long)m) - 1))
      atomicAdd(&counts[ee], (unsigned)__popcll(m));
  }
}

__global__ void tables_kernel(unsigned* __restrict__ hdr, int* __restrict__ tile_expert,
                              int* __restrict__ rows)
{
  __shared__ unsigned offs_s[NEXP+1];
  __shared__ unsigned cnt_s[NEXP];
  if (threadIdx.x == 0){
    unsigned o = 0, tt = 0;
    for (int e = 0; e < NEXP; ++e){
      unsigned c = hdr[e];
      cnt_s[e] = c;
      offs_s[e] = o;
      hdr[8 + e] = o;
      unsigned nt = (c + 127u) / 128u;
      for (unsigned k = 0; k < nt; ++k) tile_expert[tt++] = e;
      o += nt * 128u;
    }
    offs_s[NEXP] = o;
    hdr[16] = tt;
  }
  __syncthreads();
  for (int e = 0; e < NEXP; ++e){
    unsigned start = offs_s[e] + cnt_s[e];
    unsigned end   = offs_s[e+1];
    for (unsigned i = start + threadIdx.x; i < end; i += blockDim.x)
      rows[i] = 0;
  }
}

__global__ __launch_bounds__(256) void scatter_kernel(const int* __restrict__ te,
                               unsigned* __restrict__ cursor, int* __restrict__ rows,
                               int* __restrict__ slot_idx)
{
  int id = blockIdx.x * 256 + threadIdx.x;
  int tok = id >> 1;
  int e = te[id];
  int lane = threadIdx.x & 63;
  unsigned long long below = ((unsigned long long)1 << lane) - 1ull;
  unsigned myslot = 0;
  #pragma unroll
  for (int ee = 0; ee < 8; ++ee){
    unsigned long long m = __ballot(e == ee);
    if (e == ee){
      int leader = __ffsll((unsigned long long)m) - 1;
      unsigned base = 0;
      if (lane == leader) base = atomicAdd(&cursor[ee], (unsigned)__popcll(m));
      base = __shfl(base, leader, 64);
      myslot = base + (unsigned)__popcll(m & below);
    }
  }
  rows[myslot] = tok;
  slot_idx[id] = (int)myslot;
}

// ---- grouped GEMMs: 128x256 tile, BK=32, 8 waves (2x4), wave tile 64x64 acc[4][4] ----
// LDS A[2][128][32] + B[2][256][32] = 48 KB. 0.5 ds_read per MFMA (vs 0.75 at BN=128).
// dbuf + counted vmcnt(3): per thread stages 1 A-chunk + 2 B-chunks per K-step.
// Swizzle identical to R14/R16 (row bits 1-2 come from l15 / staging lane bits).
__global__ __launch_bounds__(512) void gemm1_kernel(
    const unsigned short* __restrict__ Xb,   // [NTOK][DIM]
    const unsigned short* __restrict__ W1t,  // [E][HDIM][DIM]
    const float* __restrict__ b1,
    const int* __restrict__ rows, const int* __restrict__ tile_expert,
    const unsigned* __restrict__ hdr,
    unsigned short* __restrict__ H)          // [MAXSLOT][HDIM]
{
  const int w  = swz_wid();
  const int xn = w % (int)gridDim.x;
  const int tg = w / (int)gridDim.x;
  if (tg >= (int)hdr[16]) return;
  const int e  = tile_expert[tg];
  const int n0 = xn * 256;
  const int tid = threadIdx.x;
  const int wid = tid >> 6, lane = tid & 63;
  const int wr = wid >> 2, wc = wid & 3;     // 2 x 4 wave grid, wave tile 64x64
  const int l15 = lane & 15, lq = lane >> 4;
  const int srow = wid*16 + (lane >> 2);     // staging row (0..127)
  const int schunk = (lane & 3) ^ ((lane >> 3) & 3);   // pre-swizzled source chunk
  const int rch = (lq ^ ((l15 >> 1) & 3)) * 8;         // swizzled read chunk (bf16 elems)

  __shared__ __align__(16) unsigned short As[2][128][32];
  __shared__ __align__(16) unsigned short Bs[2][256][32];

  const int tokr = rows[tg*128 + srow];
  const unsigned short* aRow  = Xb  + (size_t)tokr * DIM + schunk*8;
  const unsigned short* bRow0 = W1t + ((size_t)e * HDIM + n0 + srow      ) * DIM + schunk*8;
  const unsigned short* bRow1 = W1t + ((size_t)e * HDIM + n0 + srow + 128) * DIM + schunk*8;

  f32x4 acc[4][4];
  #pragma unroll
  for (int m = 0; m < 4; ++m)
    #pragma unroll
    for (int n = 0; n < 4; ++n) acc[m][n] = (f32x4)(0.0f);

  auto stage = [&](int b, int kk){
    gl_lds16(aRow  + kk, &As[b][wid*16][0]);
    gl_lds16(bRow0 + kk, &Bs[b][wid*16][0]);
    gl_lds16(bRow1 + kk, &Bs[b][128 + wid*16][0]);
  };

  stage(0, 0);
  __builtin_amdgcn_sched_barrier(0);

  const int NT = DIM / 32;  // 32
  int cur = 0;
  for (int t = 0; t < NT; ++t){
    if (t + 1 < NT){
      stage(cur ^ 1, (t + 1) * 32);
      __builtin_amdgcn_sched_barrier(0);
      asm volatile("s_waitcnt vmcnt(3)" ::: "memory");   // step t landed; t+1 in flight
    } else {
      asm volatile("s_waitcnt vmcnt(0)" ::: "memory");
    }
    __builtin_amdgcn_sched_barrier(0);
    __builtin_amdgcn_s_barrier();
    __builtin_amdgcn_sched_barrier(0);

    bf16x8 af[4], bfv[4];
    #pragma unroll
    for (int m = 0; m < 4; ++m)
      af[m] = *reinterpret_cast<const bf16x8*>(&As[cur][wr*64 + m*16 + l15][rch]);
    #pragma unroll
    for (int n = 0; n < 4; ++n)
      bfv[n] = *reinterpret_cast<const bf16x8*>(&Bs[cur][wc*64 + n*16 + l15][rch]);
    __builtin_amdgcn_s_setprio(1);
    #pragma unroll
    for (int m = 0; m < 4; ++m)
      #pragma unroll
      for (int n = 0; n < 4; ++n)
        acc[m][n] = __builtin_amdgcn_mfma_f32_16x16x32_bf16(af[m], bfv[n], acc[m][n], 0, 0, 0);
    __builtin_amdgcn_s_setprio(0);
    __builtin_amdgcn_sched_barrier(0);
    __builtin_amdgcn_s_barrier();   // reads of buf[cur] done before its overwrite
    __builtin_amdgcn_sched_barrier(0);
    cur ^= 1;
  }

  const int hrow0 = tg * 128;
  #pragma unroll
  for (int n = 0; n < 4; ++n){
    int c = n0 + wc*64 + n*16 + l15;
    float bv = b1[(size_t)e * HDIM + c];
    #pragma unroll
    for (int m = 0; m < 4; ++m){
      #pragma unroll
      for (int j = 0; j < 4; ++j){
        int rloc = wr*64 + m*16 + lq*4 + j;
        float v = fmaxf(acc[m][n][j] + bv, 0.0f);
        H[(size_t)(hrow0 + rloc) * HDIM + c] = f2bf(v);
      }
    }
  }
}

__global__ __launch_bounds__(512) void gemm2_kernel(
    const unsigned short* __restrict__ H,    // [MAXSLOT][HDIM]
    const unsigned short* __restrict__ W2t,  // [E][DIM][HDIM]
    const float* __restrict__ b2,
    const int* __restrict__ tile_expert, const unsigned* __restrict__ hdr,
    unsigned short* __restrict__ O2)         // [MAXSLOT][DIM]
{
  const int w  = swz_wid();
  const int xn = w % (int)gridDim.x;
  const int tg = w / (int)gridDim.x;
  if (tg >= (int)hdr[16]) return;
  const int e  = tile_expert[tg];
  const int n0 = xn * 256;
  const int tid = threadIdx.x;
  const int wid = tid >> 6, lane = tid & 63;
  const int wr = wid >> 2, wc = wid & 3;
  const int l15 = lane & 15, lq = lane >> 4;
  const int srow = wid*16 + (lane >> 2);
  const int schunk = (lane & 3) ^ ((lane >> 3) & 3);
  const int rch = (lq ^ ((l15 >> 1) & 3)) * 8;

  __shared__ __align__(16) unsigned short As[2][128][32];
  __shared__ __align__(16) unsigned short Bs[2][256][32];

  const unsigned short* aRow  = H   + (size_t)(tg*128 + srow) * HDIM + schunk*8;
  const unsigned short* bRow0 = W2t + ((size_t)e * DIM + n0 + srow      ) * HDIM + schunk*8;
  const unsigned short* bRow1 = W2t + ((size_t)e * DIM + n0 + srow + 128) * HDIM + schunk*8;

  f32x4 acc[4][4];
  #pragma unroll
  for (int m = 0; m < 4; ++m)
    #pragma unroll
    for (int n = 0; n < 4; ++n) acc[m][n] = (f32x4)(0.0f);

  auto stage = [&](int b, int kk){
    gl_lds16(aRow  + kk, &As[b][wid*16][0]);
    gl_lds16(bRow0 + kk, &Bs[b][wid*16][0]);
    gl_lds16(bRow1 + kk, &Bs[b][128 + wid*16][0]);
  };

  stage(0, 0);
  __builtin_amdgcn_sched_barrier(0);

  const int NT = HDIM / 32;  // 128
  int cur = 0;
  for (int t = 0; t < NT; ++t){
    if (t + 1 < NT){
      stage(cur ^ 1, (t + 1) * 32);
      __builtin_amdgcn_sched_barrier(0);
      asm volatile("s_waitcnt vmcnt(3)" ::: "memory");
    } else {
      asm volatile("s_waitcnt vmcnt(0)" ::: "memory");
    }
    __builtin_amdgcn_sched_barrier(0);
    __builtin_amdgcn_s_barrier();
    __builtin_amdgcn_sched_barrier(0);

    bf16x8 af[4], bfv[4];
    #pragma unroll
    for (int m = 0; m < 4; ++m)
      af[m] = *reinterpret_cast<const bf16x8*>(&As[cur][wr*64 + m*16 + l15][rch]);
    #pragma unroll
    for (int n = 0; n < 4; ++n)
      bfv[n] = *reinterpret_cast<const bf16x8*>(&Bs[cur][wc*64 + n*16 + l15][rch]);
    __builtin_amdgcn_s_setprio(1);
    #pragma unroll
    for (int m = 0; m < 4; ++m)
      #pragma unroll
      for (int n = 0; n < 4; ++n)
        acc[m][n] = __builtin_amdgcn_mfma_f32_16x16x32_bf16(af[m], bfv[n], acc[m][n], 0, 0, 0);
    __builtin_amdgcn_s_setprio(0);
    __builtin_amdgcn_sched_barrier(0);
    __builtin_amdgcn_s_barrier();
    __builtin_amdgcn_sched_barrier(0);
    cur ^= 1;
  }

  #pragma unroll
  for (int n = 0; n < 4; ++n){
    int c = n0 + wc*64 + n*16 + l15;
    float bv = b2[(size_t)e * DIM + c];
    #pragma unroll
    for (int m = 0; m < 4; ++m){
      #pragma unroll
      for (int j = 0; j < 4; ++j){
        int rloc = wr*64 + m*16 + lq*4 + j;
        O2[(size_t)(tg*128 + rloc) * DIM + c] = f2bf(acc[m][n][j] + bv);
      }
    }
  }
}

// out[tok] = g0*O2[s0] + g1*O2[s1]  (fp32, fixed order -> deterministic)
__global__ __launch_bounds__(256) void combine_kernel(
    const unsigned short* __restrict__ O2, const int* __restrict__ slot_idx,
    const float* __restrict__ tgv, float* __restrict__ out)
{
  int tok = blockIdx.x;
  int d4  = threadIdx.x;
  int s0 = slot_idx[tok*2], s1 = slot_idx[tok*2 + 1];
  float g0 = tgv[tok*2], g1 = tgv[tok*2 + 1];
  ushort4 a = ((const ushort4*)(O2 + (size_t)s0 * DIM))[d4];
  ushort4 b = ((const ushort4*)(O2 + (size_t)s1 * DIM))[d4];
  float4 o;
  o.x = g0*bf2f(a.x) + g1*bf2f(b.x);
  o.y = g0*bf2f(a.y) + g1*bf2f(b.y);
  o.z = g0*bf2f(a.z) + g1*bf2f(b.z);
  o.w = g0*bf2f(a.w) + g1*bf2f(b.w);
  ((float4*)(out + (size_t)tok * DIM))[d4] = o;
}

// ---------------- host ----------------
extern "C" void kernel_launch(void* const* d_in, const int* in_sizes, int n_in,
                              void* d_out, int out_size, void* d_ws, size_t ws_size,
                              hipStream_t stream)
{
  const float* x  = (const float*)d_in[0];
  const int*   moe= (const int*)  d_in[1];
  const float* Wr = (const float*)d_in[2];
  const float* br = (const float*)d_in[3];
  const float* Wn = (const float*)d_in[4];
  const float* bn = (const float*)d_in[5];
  const float* W1 = (const float*)d_in[6];
  const float* b1 = (const float*)d_in[7];
  const float* W2 = (const float*)d_in[8];
  const float* b2 = (const float*)d_in[9];
  float* out = (float*)d_out;
  float* topi_out = out + (size_t)NTOK * DIM;

  char* ws = (char*)d_ws;
  size_t off = 0;
  auto take = [&](size_t bytes)->char*{
    char* p = ws + off;
    off = (off + bytes + 255) & ~(size_t)255;
    return p;
  };
  unsigned* hdr        = (unsigned*)take(128);
  int*      tile_exp   = (int*)     take(MAXTILES * 4);
  int*      rows       = (int*)     take(MAXSLOT * 4);
  int*      te         = (int*)     take(NSLOT * 4);
  float*    tgv        = (float*)   take(NSLOT * 4);
  int*      slot_idx   = (int*)     take(NSLOT * 4);
  unsigned short* xb   = (unsigned short*)take((size_t)NTOK * DIM * 2);
  unsigned short* W1t  = (unsigned short*)take((size_t)NEXP * HDIM * DIM * 2);
  unsigned short* W2t  = (unsigned short*)take((size_t)NEXP * DIM * HDIM * 2);
  unsigned short* O2   = (unsigned short*)take((size_t)MAXSLOT * DIM * 2);

  size_t avail = (ws_size > off) ? (ws_size - off) : 0;
  size_t maxrows = avail / ((size_t)HDIM * 2);
  int tpc = (int)(maxrows / 128);
  if (tpc > MAXTILES) tpc = MAXTILES;
  if (tpc < 1) tpc = 1;
  unsigned short* H = (unsigned short*)take((size_t)tpc * 128 * HDIM * 2);

  hipMemsetAsync(hdr, 0, 128, stream);

  transpose_both_kernel<<<65536, 256, 0, stream>>>(W1, W2, W1t, W2t);
  route_kernel<<<NTOK/4, 256, 0, stream>>>(x, moe, Wr, br, Wn, bn, topi_out, te, tgv, xb);
  count_kernel<<<NSLOT/256, 256, 0, stream>>>(te, hdr);
  tables_kernel<<<1, 64, 0, stream>>>(hdr, tile_exp, rows);
  scatter_kernel<<<NSLOT/256, 256, 0, stream>>>(te, hdr + 8, rows, slot_idx);

  if (tpc >= MAXTILES){
    gemm1_kernel<<<dim3(HDIM/256, MAXTILES), 512, 0, stream>>>(xb, W1t, b1, rows, tile_exp, hdr, H);
    gemm2_kernel<<<dim3(DIM/256,  MAXTILES), 512, 0, stream>>>(H, W2t, b2, tile_exp, hdr, O2);
  } else {
    for (int t0 = 0; t0 < MAXTILES; t0 += tpc){
      int nt = (tpc < MAXTILES - t0) ? tpc : (MAXTILES - t0);
      unsigned short* Hoff = H - (size_t)t0 * 128 * HDIM;
      gemm1_kernel<<<dim3(HDIM/256, nt), 512, 0, stream>>>(xb, W1t, b1, rows + t0*128,
                                                           tile_exp + t0, hdr, Hoff);
      gemm2_kernel<<<dim3(DIM/256,  nt), 512, 0, stream>>>(Hoff, W2t, b2, tile_exp + t0, hdr,
                                                           O2 + (size_t)t0*128*DIM);
    }
  }
  combine_kernel<<<NTOK, 256, 0, stream>>>(O2, slot_idx, tgv, out);
}

// Round 18
// 721.204 us; speedup vs baseline: 1.0379x; 1.0379x over previous
//
#include <hip/hip_runtime.h>
#include <hip/hip_bf16.h>
#include <cstdint>

#define NTOK   10240      // 5*2048 tokens
#define DIM    1024
#define NEXP   8
#define HDIM   4096
#define NSLOT  20480      // NTOK * top2
#define MAXSLOT 21504     // padded to 128 per expert (168*128)
#define MAXTILES 168

typedef __attribute__((ext_vector_type(8))) __bf16 bf16x8;
typedef __attribute__((ext_vector_type(4))) float  f32x4;

__device__ __forceinline__ unsigned short f2bf(float f){
  uint32_t u = __float_as_uint(f);
  uint32_t r = (u + 0x7fffu + ((u >> 16) & 1u)) >> 16;   // RNE
  return (unsigned short)r;
}
__device__ __forceinline__ float bf2f(unsigned short u){
  return __uint_as_float(((uint32_t)u) << 16);
}

__device__ __forceinline__ void gl_lds16(const void* g, void* l){
  __builtin_amdgcn_global_load_lds(
      (const __attribute__((address_space(1))) void*)g,
      (__attribute__((address_space(3))) void*)l, 16, 0, 0);
}

// bijective XCD swizzle (m204)
__device__ __forceinline__ int swz_wid(){
  int nwg = (int)(gridDim.x * gridDim.y);
  int h   = (int)(blockIdx.y * gridDim.x + blockIdx.x);
  int q = nwg >> 3, r = nwg & 7;
  int xcd = h & 7, idx = h >> 3;
  return (xcd < r ? xcd*(q+1) : r*(q+1) + (xcd-r)*q) + idx;
}

// ---------------- Threefry2x32 (JAX partitionable path) ----------------
__device__ __forceinline__ uint32_t rotl32(uint32_t x, int n){ return (x << n) | (x >> (32 - n)); }

__device__ __forceinline__ uint32_t threefry_xor(uint32_t k0, uint32_t k1, uint32_t x0, uint32_t x1){
  uint32_t ks2 = k0 ^ k1 ^ 0x1BD11BDAu;
  uint32_t ks[3] = {k0, k1, ks2};
  x0 += ks[0]; x1 += ks[1];
  const int rA[4] = {13,15,26,6};
  const int rB[4] = {17,29,16,24};
  #pragma unroll
  for (int i = 0; i < 5; ++i){
    #pragma unroll
    for (int j = 0; j < 4; ++j){
      int rot = (i & 1) ? rB[j] : rA[j];
      x0 += x1; x1 = rotl32(x1, rot); x1 ^= x0;
    }
    x0 += ks[(i+1)%3];
    x1 += ks[(i+2)%3] + (uint32_t)(i+1);
  }
  return x0 ^ x1;
}

// XLA f32 ErfInv (Giles polynomial)
__device__ __forceinline__ float erfinv_f32(float x){
  float w = -log1pf(-x*x);
  float p;
  if (w < 5.0f){
    w -= 2.5f;
    p = 2.81022636e-08f;
    p = fmaf(p, w, 3.43273939e-07f);
    p = fmaf(p, w, -3.5233877e-06f);
    p = fmaf(p, w, -4.39150654e-06f);
    p = fmaf(p, w, 0.00021858087f);
    p = fmaf(p, w, -0.00125372503f);
    p = fmaf(p, w, -0.00417768164f);
    p = fmaf(p, w, 0.246640727f);
    p = fmaf(p, w, 1.50140941f);
  } else {
    w = sqrtf(w) - 3.0f;
    p = -0.000200214257f;
    p = fmaf(p, w, 0.000100950558f);
    p = fmaf(p, w, 0.00134934322f);
    p = fmaf(p, w, -0.00367342844f);
    p = fmaf(p, w, 0.00573950773f);
    p = fmaf(p, w, -0.0076224613f);
    p = fmaf(p, w, 0.00943887047f);
    p = fmaf(p, w, 1.00167406f);
    p = fmaf(p, w, 2.83297682f);
  }
  return p * x;
}

// ---------------- merged weight transposes: one dispatch for W1 and W2 ----------------
__device__ __forceinline__ void transpose_body(const float* __restrict__ src,
                                               unsigned short* __restrict__ dst,
                                               int R_, int C_, int bx, int by, int z){
  __shared__ float tile[32][33];
  const int tx = threadIdx.x & 31, ty = threadIdx.x >> 5;
  const float* s = src + (size_t)z * R_ * C_;
  unsigned short* d = dst + (size_t)z * R_ * C_;
  int c0 = bx * 32, r0 = by * 32;
  #pragma unroll
  for (int i = ty; i < 32; i += 8)
    tile[i][tx] = s[(size_t)(r0 + i) * C_ + c0 + tx];
  __syncthreads();
  #pragma unroll
  for (int i = ty; i < 32; i += 8)
    d[(size_t)(c0 + i) * R_ + r0 + tx] = f2bf(tile[tx][i]);
}

__global__ __launch_bounds__(256) void transpose_both_kernel(
    const float* __restrict__ W1, const float* __restrict__ W2,
    unsigned short* __restrict__ W1t, unsigned short* __restrict__ W2t)
{
  int i = (int)blockIdx.x;
  if (i < 32768){   // W1 [8][1024][4096] -> W1t [8][4096][1024]
    transpose_body(W1, W1t, DIM, HDIM, i & 127, (i >> 7) & 31, i >> 12);
  } else {          // W2 [8][4096][1024] -> W2t [8][1024][4096]
    i -= 32768;
    transpose_body(W2, W2t, HDIM, DIM, i & 31, (i >> 5) & 127, i >> 12);
  }
}

// ---------------- routing: 4 waves/block, 1 wave per token ----------------
__global__ __launch_bounds__(256) void route_kernel(
    const float* __restrict__ x, const int* __restrict__ moe,
    const float* __restrict__ Wr, const float* __restrict__ br,
    const float* __restrict__ Wn, const float* __restrict__ bn,
    float* __restrict__ topi_out, int* __restrict__ te, float* __restrict__ tgv,
    unsigned short* __restrict__ xb)
{
  const int wv = threadIdx.x >> 6, lane = threadIdx.x & 63;
  const int tok = (int)blockIdx.x * 4 + wv;
  const int b = tok >> 11;
  const int r = moe[b];
  const float4* xr  = (const float4*)(x + (size_t)tok * DIM);
  const float4* wrp = (const float4*)(Wr + (size_t)r * DIM * NEXP);
  const float4* wnp = (const float4*)(Wn + (size_t)r * DIM * NEXP);
  ushort4* xbrow = (ushort4*)(xb + (size_t)tok * DIM);

  float lg[8], nl[8];
  #pragma unroll
  for (int e = 0; e < 8; ++e){ lg[e] = 0.f; nl[e] = 0.f; }

  #pragma unroll
  for (int it = 0; it < 4; ++it){
    int d4 = it*64 + lane;
    float4 xv = xr[d4];
    ushort4 o;
    o.x = f2bf(xv.x); o.y = f2bf(xv.y); o.z = f2bf(xv.z); o.w = f2bf(xv.w);
    xbrow[d4] = o;
    #pragma unroll
    for (int j = 0; j < 4; ++j){
      float xs = (j==0) ? xv.x : (j==1) ? xv.y : (j==2) ? xv.z : xv.w;
      float4 w0 = wrp[d4*8 + j*2], w1 = wrp[d4*8 + j*2 + 1];
      float4 n0 = wnp[d4*8 + j*2], n1 = wnp[d4*8 + j*2 + 1];
      lg[0] = fmaf(xs, w0.x, lg[0]); lg[1] = fmaf(xs, w0.y, lg[1]);
      lg[2] = fmaf(xs, w0.z, lg[2]); lg[3] = fmaf(xs, w0.w, lg[3]);
      lg[4] = fmaf(xs, w1.x, lg[4]); lg[5] = fmaf(xs, w1.y, lg[5]);
      lg[6] = fmaf(xs, w1.z, lg[6]); lg[7] = fmaf(xs, w1.w, lg[7]);
      nl[0] = fmaf(xs, n0.x, nl[0]); nl[1] = fmaf(xs, n0.y, nl[1]);
      nl[2] = fmaf(xs, n0.z, nl[2]); nl[3] = fmaf(xs, n0.w, nl[3]);
      nl[4] = fmaf(xs, n1.x, nl[4]); nl[5] = fmaf(xs, n1.y, nl[5]);
      nl[6] = fmaf(xs, n1.z, nl[6]); nl[7] = fmaf(xs, n1.w, nl[7]);
    }
  }

  #pragma unroll
  for (int e = 0; e < 8; ++e){
    #pragma unroll
    for (int s = 32; s >= 1; s >>= 1){
      lg[e] += __shfl_xor(lg[e], s, 64);
      nl[e] += __shfl_xor(nl[e], s, 64);
    }
  }

  int el = lane & 7;
  float mylg = lg[0], mynl = nl[0];
  #pragma unroll
  for (int e = 1; e < 8; ++e){
    if (el == e){ mylg = lg[e]; mynl = nl[e]; }
  }
  float logit = mylg + br[r*NEXP + el];
  float nlg   = mynl + bn[r*NEXP + el];
  uint32_t idx  = (uint32_t)(tok*NEXP + el);
  uint32_t bits = threefry_xor(0u, 42u, 0u, idx);
  float u01 = __uint_as_float((bits >> 9) | 0x3f800000u) - 1.0f;
  const float lo = -0.99999994f;
  float uu  = fmaxf(lo, u01 * 2.0f + lo);
  float eps = 1.41421356237f * erfinv_f32(uu);
  float ax = fabsf(nlg);
  float sp = fmaxf(nlg, 0.0f) + log1pf(expf(-ax));
  float noisy = logit + eps * sp;

  float nv[8];
  #pragma unroll
  for (int e = 0; e < 8; ++e) nv[e] = __shfl(noisy, e, 64);

  if (lane == 0){
    int i0 = 0; float v0 = nv[0];
    int i1 = -1; float v1 = -3.4e38f;
    #pragma unroll
    for (int e = 1; e < 8; ++e){
      float v = nv[e];
      if (v > v0){ v1 = v0; i1 = i0; v0 = v; i0 = e; }
      else if (v > v1){ v1 = v; i1 = e; }
    }
    float t = expf(v1 - v0);
    float s = 1.0f + t;
    topi_out[tok*2 + 0] = (float)i0;
    topi_out[tok*2 + 1] = (float)i1;
    te[tok*2 + 0] = i0; te[tok*2 + 1] = i1;
    tgv[tok*2 + 0] = 1.0f / s; tgv[tok*2 + 1] = t / s;
  }
}

// ---------------- count / tables / scatter ----------------
// hdr: [0..8) counts, [8..16) cursor, [16] ntiles
__global__ __launch_bounds__(256) void count_kernel(const int* __restrict__ te,
                                                    unsigned* __restrict__ counts){
  int id = blockIdx.x * 256 + threadIdx.x;
  int e = te[id];
  int lane = threadIdx.x & 63;
  #pragma unroll
  for (int ee = 0; ee < 8; ++ee){
    unsigned long long m = __ballot(e == ee);
    if (m && lane == (__ffsll((unsigned long long)m) - 1))
      atomicAdd(&counts[ee], (unsigned)__popcll(m));
  }
}

__global__ void tables_kernel(unsigned* __restrict__ hdr, int* __restrict__ tile_expert,
                              int* __restrict__ rows)
{
  __shared__ unsigned offs_s[NEXP+1];
  __shared__ unsigned cnt_s[NEXP];
  if (threadIdx.x == 0){
    unsigned o = 0, tt = 0;
    for (int e = 0; e < NEXP; ++e){
      unsigned c = hdr[e];
      cnt_s[e] = c;
      offs_s[e] = o;
      hdr[8 + e] = o;
      unsigned nt = (c + 127u) / 128u;
      for (unsigned k = 0; k < nt; ++k) tile_expert[tt++] = e;
      o += nt * 128u;
    }
    offs_s[NEXP] = o;
    hdr[16] = tt;
  }
  __syncthreads();
  for (int e = 0; e < NEXP; ++e){
    unsigned start = offs_s[e] + cnt_s[e];
    unsigned end   = offs_s[e+1];
    for (unsigned i = start + threadIdx.x; i < end; i += blockDim.x)
      rows[i] = 0;
  }
}

__global__ __launch_bounds__(256) void scatter_kernel(const int* __restrict__ te,
                               unsigned* __restrict__ cursor, int* __restrict__ rows,
                               int* __restrict__ slot_idx)
{
  int id = blockIdx.x * 256 + threadIdx.x;
  int tok = id >> 1;
  int e = te[id];
  int lane = threadIdx.x & 63;
  unsigned long long below = ((unsigned long long)1 << lane) - 1ull;
  unsigned myslot = 0;
  #pragma unroll
  for (int ee = 0; ee < 8; ++ee){
    unsigned long long m = __ballot(e == ee);
    if (e == ee){
      int leader = __ffsll((unsigned long long)m) - 1;
      unsigned base = 0;
      if (lane == leader) base = atomicAdd(&cursor[ee], (unsigned)__popcll(m));
      base = __shfl(base, leader, 64);
      myslot = base + (unsigned)__popcll(m & below);
    }
  }
  rows[myslot] = tok;
  slot_idx[id] = (int)myslot;
}

// ---- grouped GEMMs (R14/R16, best measured): 128x128, BK=32, 8 waves acc[4][2], ----
// ---- dbuf+counted vmcnt(2), 32 KB LDS -> 4 blocks/CU = 32 waves/CU, conflicts 0. ----
// 64B-row swizzle: LDS[r][c] holds global chunk c^((r>>1)&3);
// staging src chunk (l&3)^((l>>3)&3); read chunk lq^((l15>>1)&3) -> 2-way = free.
__global__ __launch_bounds__(512) void gemm1_kernel(
    const unsigned short* __restrict__ Xb,   // [NTOK][DIM]
    const unsigned short* __restrict__ W1t,  // [E][HDIM][DIM]
    const float* __restrict__ b1,
    const int* __restrict__ rows, const int* __restrict__ tile_expert,
    const unsigned* __restrict__ hdr,
    unsigned short* __restrict__ H)          // [MAXSLOT][HDIM]
{
  const int w  = swz_wid();
  const int xn = w % (int)gridDim.x;
  const int tg = w / (int)gridDim.x;
  if (tg >= (int)hdr[16]) return;
  const int e  = tile_expert[tg];
  const int n0 = xn * 128;
  const int tid = threadIdx.x;
  const int wid = tid >> 6, lane = tid & 63;
  const int wr = wid >> 2, wc = wid & 3;     // 2 x 4 wave grid
  const int l15 = lane & 15, lq = lane >> 4;
  const int srow = wid*16 + (lane >> 2);     // staging row
  const int schunk = (lane & 3) ^ ((lane >> 3) & 3);   // pre-swizzled source chunk
  const int rch = (lq ^ ((l15 >> 1) & 3)) * 8;         // swizzled read chunk (bf16 elems)

  __shared__ __align__(16) unsigned short As[2][128][32];
  __shared__ __align__(16) unsigned short Bs[2][128][32];

  const int tokr = rows[tg*128 + srow];
  const unsigned short* aRow = Xb  + (size_t)tokr * DIM + schunk*8;
  const unsigned short* bRow = W1t + ((size_t)e * HDIM + n0 + srow) * DIM + schunk*8;

  f32x4 acc[4][2];
  #pragma unroll
  for (int m = 0; m < 4; ++m)
    #pragma unroll
    for (int n = 0; n < 2; ++n) acc[m][n] = (f32x4)(0.0f);

  auto stage = [&](int b, int kk){
    gl_lds16(aRow + kk, &As[b][wid*16][0]);
    gl_lds16(bRow + kk, &Bs[b][wid*16][0]);
  };

  stage(0, 0);
  __builtin_amdgcn_sched_barrier(0);

  const int NT = DIM / 32;  // 32
  int cur = 0;
  for (int t = 0; t < NT; ++t){
    if (t + 1 < NT){
      stage(cur ^ 1, (t + 1) * 32);
      __builtin_amdgcn_sched_barrier(0);
      asm volatile("s_waitcnt vmcnt(2)" ::: "memory");   // step t landed; t+1 in flight
    } else {
      asm volatile("s_waitcnt vmcnt(0)" ::: "memory");
    }
    __builtin_amdgcn_sched_barrier(0);
    __builtin_amdgcn_s_barrier();
    __builtin_amdgcn_sched_barrier(0);

    bf16x8 af[4], bfv[2];
    #pragma unroll
    for (int m = 0; m < 4; ++m)
      af[m] = *reinterpret_cast<const bf16x8*>(&As[cur][wr*64 + m*16 + l15][rch]);
    #pragma unroll
    for (int n = 0; n < 2; ++n)
      bfv[n] = *reinterpret_cast<const bf16x8*>(&Bs[cur][wc*32 + n*16 + l15][rch]);
    __builtin_amdgcn_s_setprio(1);
    #pragma unroll
    for (int m = 0; m < 4; ++m)
      #pragma unroll
      for (int n = 0; n < 2; ++n)
        acc[m][n] = __builtin_amdgcn_mfma_f32_16x16x32_bf16(af[m], bfv[n], acc[m][n], 0, 0, 0);
    __builtin_amdgcn_s_setprio(0);
    __builtin_amdgcn_sched_barrier(0);
    __builtin_amdgcn_s_barrier();   // reads of buf[cur] done before its overwrite
    __builtin_amdgcn_sched_barrier(0);
    cur ^= 1;
  }

  const int hrow0 = tg * 128;
  #pragma unroll
  for (int n = 0; n < 2; ++n){
    int c = n0 + wc*32 + n*16 + l15;
    float bv = b1[(size_t)e * HDIM + c];
    #pragma unroll
    for (int m = 0; m < 4; ++m){
      #pragma unroll
      for (int j = 0; j < 4; ++j){
        int rloc = wr*64 + m*16 + lq*4 + j;
        float v = fmaxf(acc[m][n][j] + bv, 0.0f);
        H[(size_t)(hrow0 + rloc) * HDIM + c] = f2bf(v);
      }
    }
  }
}

__global__ __launch_bounds__(512) void gemm2_kernel(
    const unsigned short* __restrict__ H,    // [MAXSLOT][HDIM]
    const unsigned short* __restrict__ W2t,  // [E][DIM][HDIM]
    const float* __restrict__ b2,
    const int* __restrict__ tile_expert, const unsigned* __restrict__ hdr,
    unsigned short* __restrict__ O2)         // [MAXSLOT][DIM]
{
  const int w  = swz_wid();
  const int xn = w % (int)gridDim.x;
  const int tg = w / (int)gridDim.x;
  if (tg >= (int)hdr[16]) return;
  const int e  = tile_expert[tg];
  const int n0 = xn * 128;
  const int tid = threadIdx.x;
  const int wid = tid >> 6, lane = tid & 63;
  const int wr = wid >> 2, wc = wid & 3;
  const int l15 = lane & 15, lq = lane >> 4;
  const int srow = wid*16 + (lane >> 2);
  const int schunk = (lane & 3) ^ ((lane >> 3) & 3);
  const int rch = (lq ^ ((l15 >> 1) & 3)) * 8;

  __shared__ __align__(16) unsigned short As[2][128][32];
  __shared__ __align__(16) unsigned short Bs[2][128][32];

  const unsigned short* aRow = H   + (size_t)(tg*128 + srow) * HDIM + schunk*8;
  const unsigned short* bRow = W2t + ((size_t)e * DIM + n0 + srow) * HDIM + schunk*8;

  f32x4 acc[4][2];
  #pragma unroll
  for (int m = 0; m < 4; ++m)
    #pragma unroll
    for (int n = 0; n < 2; ++n) acc[m][n] = (f32x4)(0.0f);

  auto stage = [&](int b, int kk){
    gl_lds16(aRow + kk, &As[b][wid*16][0]);
    gl_lds16(bRow + kk, &Bs[b][wid*16][0]);
  };

  stage(0, 0);
  __builtin_amdgcn_sched_barrier(0);

  const int NT = HDIM / 32;  // 128
  int cur = 0;
  for (int t = 0; t < NT; ++t){
    if (t + 1 < NT){
      stage(cur ^ 1, (t + 1) * 32);
      __builtin_amdgcn_sched_barrier(0);
      asm volatile("s_waitcnt vmcnt(2)" ::: "memory");
    } else {
      asm volatile("s_waitcnt vmcnt(0)" ::: "memory");
    }
    __builtin_amdgcn_sched_barrier(0);
    __builtin_amdgcn_s_barrier();
    __builtin_amdgcn_sched_barrier(0);

    bf16x8 af[4], bfv[2];
    #pragma unroll
    for (int m = 0; m < 4; ++m)
      af[m] = *reinterpret_cast<const bf16x8*>(&As[cur][wr*64 + m*16 + l15][rch]);
    #pragma unroll
    for (int n = 0; n < 2; ++n)
      bfv[n] = *reinterpret_cast<const bf16x8*>(&Bs[cur][wc*32 + n*16 + l15][rch]);
    __builtin_amdgcn_s_setprio(1);
    #pragma unroll
    for (int m = 0; m < 4; ++m)
      #pragma unroll
      for (int n = 0; n < 2; ++n)
        acc[m][n] = __builtin_amdgcn_mfma_f32_16x16x32_bf16(af[m], bfv[n], acc[m][n], 0, 0, 0);
    __builtin_amdgcn_s_setprio(0);
    __builtin_amdgcn_sched_barrier(0);
    __builtin_amdgcn_s_barrier();
    __builtin_amdgcn_sched_barrier(0);
    cur ^= 1;
  }

  #pragma unroll
  for (int n = 0; n < 2; ++n){
    int c = n0 + wc*32 + n*16 + l15;
    float bv = b2[(size_t)e * DIM + c];
    #pragma unroll
    for (int m = 0; m < 4; ++m){
      #pragma unroll
      for (int j = 0; j < 4; ++j){
        int rloc = wr*64 + m*16 + lq*4 + j;
        O2[(size_t)(tg*128 + rloc) * DIM + c] = f2bf(acc[m][n][j] + bv);
      }
    }
  }
}

// out[tok] = g0*O2[s0] + g1*O2[s1]  (fp32, fixed order -> deterministic)
__global__ __launch_bounds__(256) void combine_kernel(
    const unsigned short* __restrict__ O2, const int* __restrict__ slot_idx,
    const float* __restrict__ tgv, float* __restrict__ out)
{
  int tok = blockIdx.x;
  int d4  = threadIdx.x;
  int s0 = slot_idx[tok*2], s1 = slot_idx[tok*2 + 1];
  float g0 = tgv[tok*2], g1 = tgv[tok*2 + 1];
  ushort4 a = ((const ushort4*)(O2 + (size_t)s0 * DIM))[d4];
  ushort4 b = ((const ushort4*)(O2 + (size_t)s1 * DIM))[d4];
  float4 o;
  o.x = g0*bf2f(a.x) + g1*bf2f(b.x);
  o.y = g0*bf2f(a.y) + g1*bf2f(b.y);
  o.z = g0*bf2f(a.z) + g1*bf2f(b.z);
  o.w = g0*bf2f(a.w) + g1*bf2f(b.w);
  ((float4*)(out + (size_t)tok * DIM))[d4] = o;
}

// ---------------- host ----------------
extern "C" void kernel_launch(void* const* d_in, const int* in_sizes, int n_in,
                              void* d_out, int out_size, void* d_ws, size_t ws_size,
                              hipStream_t stream)
{
  const float* x  = (const float*)d_in[0];
  const int*   moe= (const int*)  d_in[1];
  const float* Wr = (const float*)d_in[2];
  const float* br = (const float*)d_in[3];
  const float* Wn = (const float*)d_in[4];
  const float* bn = (const float*)d_in[5];
  const float* W1 = (const float*)d_in[6];
  const float* b1 = (const float*)d_in[7];
  const float* W2 = (const float*)d_in[8];
  const float* b2 = (const float*)d_in[9];
  float* out = (float*)d_out;
  float* topi_out = out + (size_t)NTOK * DIM;

  char* ws = (char*)d_ws;
  size_t off = 0;
  auto take = [&](size_t bytes)->char*{
    char* p = ws + off;
    off = (off + bytes + 255) & ~(size_t)255;
    return p;
  };
  unsigned* hdr        = (unsigned*)take(128);
  int*      tile_exp   = (int*)     take(MAXTILES * 4);
  int*      rows       = (int*)     take(MAXSLOT * 4);
  int*      te         = (int*)     take(NSLOT * 4);
  float*    tgv        = (float*)   take(NSLOT * 4);
  int*      slot_idx   = (int*)     take(NSLOT * 4);
  unsigned short* xb   = (unsigned short*)take((size_t)NTOK * DIM * 2);
  unsigned short* W1t  = (unsigned short*)take((size_t)NEXP * HDIM * DIM * 2);
  unsigned short* W2t  = (unsigned short*)take((size_t)NEXP * DIM * HDIM * 2);
  unsigned short* O2   = (unsigned short*)take((size_t)MAXSLOT * DIM * 2);

  size_t avail = (ws_size > off) ? (ws_size - off) : 0;
  size_t maxrows = avail / ((size_t)HDIM * 2);
  int tpc = (int)(maxrows / 128);
  if (tpc > MAXTILES) tpc = MAXTILES;
  if (tpc < 1) tpc = 1;
  unsigned short* H = (unsigned short*)take((size_t)tpc * 128 * HDIM * 2);

  hipMemsetAsync(hdr, 0, 128, stream);

  transpose_both_kernel<<<65536, 256, 0, stream>>>(W1, W2, W1t, W2t);
  route_kernel<<<NTOK/4, 256, 0, stream>>>(x, moe, Wr, br, Wn, bn, topi_out, te, tgv, xb);
  count_kernel<<<NSLOT/256, 256, 0, stream>>>(te, hdr);
  tables_kernel<<<1, 64, 0, stream>>>(hdr, tile_exp, rows);
  scatter_kernel<<<NSLOT/256, 256, 0, stream>>>(te, hdr + 8, rows, slot_idx);

  if (tpc >= MAXTILES){
    gemm1_kernel<<<dim3(HDIM/128, MAXTILES), 512, 0, stream>>>(xb, W1t, b1, rows, tile_exp, hdr, H);
    gemm2_kernel<<<dim3(DIM/128,  MAXTILES), 512, 0, stream>>>(H, W2t, b2, tile_exp, hdr, O2);
  } else {
    for (int t0 = 0; t0 < MAXTILES; t0 += tpc){
      int nt = (tpc < MAXTILES - t0) ? tpc : (MAXTILES - t0);
      unsigned short* Hoff = H - (size_t)t0 * 128 * HDIM;
      gemm1_kernel<<<dim3(HDIM/128, nt), 512, 0, stream>>>(xb, W1t, b1, rows + t0*128,
                                                           tile_exp + t0, hdr, Hoff);
      gemm2_kernel<<<dim3(DIM/128,  nt), 512, 0, stream>>>(Hoff, W2t, b2, tile_exp + t0, hdr,
                                                           O2 + (size_t)t0*128*DIM);
    }
  }
  combine_kernel<<<NTOK, 256, 0, stream>>>(O2, slot_idx, tgv, out);
}